// Round 8
// baseline (520.948 us; speedup 1.0000x reference)
//
#include <hip/hip_runtime.h>

#define Bdim 64
#define Ndim 512
#define Hdim 2048
#define KSPLIT 8
#define NCHUNK 8
#define LNEPS 1e-5f
#define WMAT_ELEMS (Hdim * Hdim)

typedef unsigned short u16;
typedef __attribute__((ext_vector_type(8))) short short8;
typedef __attribute__((ext_vector_type(4))) float f32x4;

__device__ __forceinline__ u16 f2bf(float f) {
    unsigned int u = __float_as_uint(f);
    return (u16)((u + 0x7FFFu + ((u >> 16) & 1u)) >> 16);
}
__device__ __forceinline__ float bf2f(u16 s) {
    return __uint_as_float(((unsigned int)s) << 16);
}

// One-time prep: 7 bf16 weight views in [o][k] layout + clip in bf16.
// blocks [0,5120): direct convert Wc,Wt,Wl,Wg,Wo
// blocks [5120,7168): transpose-convert Wp, Wl  -> bWpT, bWlT
// blocks [7168,7200): clip -> clip16
__global__ __launch_bounds__(256)
void convert_w(const float* __restrict__ Wc, const float* __restrict__ Wt,
               const float* __restrict__ Wl, const float* __restrict__ Wg,
               const float* __restrict__ Wo, const float* __restrict__ Wp,
               const float* __restrict__ clip,
               u16* __restrict__ dst, u16* __restrict__ clip16)
{
    __shared__ float L[64][65];
    const int t   = threadIdx.x;
    const int bid = blockIdx.x;
    if (bid < 5120) {
        const int mid = bid >> 10;
        const int tb  = bid & 1023;
        const float* src = (mid == 0) ? Wc : (mid == 1) ? Wt : (mid == 2) ? Wl
                         : (mid == 3) ? Wg : Wo;
        u16* out = dst + (size_t)mid * WMAT_ELEMS;
        const size_t base = (size_t)tb * 4096 + (size_t)t * 16;
#pragma unroll
        for (int i = 0; i < 2; ++i) {
            float4 a = *(const float4*)(src + base + i * 8);
            float4 b = *(const float4*)(src + base + i * 8 + 4);
            short8 s;
            s[0] = (short)f2bf(a.x); s[1] = (short)f2bf(a.y);
            s[2] = (short)f2bf(a.z); s[3] = (short)f2bf(a.w);
            s[4] = (short)f2bf(b.x); s[5] = (short)f2bf(b.y);
            s[6] = (short)f2bf(b.z); s[7] = (short)f2bf(b.w);
            *(short8*)(out + base + i * 8) = s;
        }
    } else if (bid < 7168) {
        const int mid = 5 + ((bid - 5120) >> 10);
        const int tb  = (bid - 5120) & 1023;
        const float* src = (mid == 5) ? Wp : Wl;
        u16* out = dst + (size_t)mid * WMAT_ELEMS;
        const int k0 = (tb & 31) * 64;
        const int o0 = (tb >> 5) * 64;
        const int row = t >> 2;
        const int cq  = t & 3;
#pragma unroll
        for (int i = 0; i < 4; ++i) {
            float4 v = *(const float4*)(src + (size_t)(k0 + row) * Hdim + o0 + cq * 16 + i * 4);
            *(float4*)(&L[row][cq * 16 + i * 4]) = v;
        }
        __syncthreads();
        const int orow = t >> 2;
#pragma unroll
        for (int half = 0; half < 2; ++half) {
            short8 s;
#pragma unroll
            for (int i = 0; i < 8; ++i)
                s[i] = (short)f2bf(L[cq * 16 + half * 8 + i][orow]);
            *(short8*)(out + (size_t)(o0 + orow) * Hdim + k0 + cq * 16 + half * 8) = s;
        }
    } else {
        const int tb = bid - 7168;   // 0..31, 4096 elems each
        const size_t base = (size_t)tb * 4096 + (size_t)t * 16;
#pragma unroll
        for (int i = 0; i < 2; ++i) {
            float4 a = *(const float4*)(clip + base + i * 8);
            float4 b = *(const float4*)(clip + base + i * 8 + 4);
            short8 s;
            s[0] = (short)f2bf(a.x); s[1] = (short)f2bf(a.y);
            s[2] = (short)f2bf(a.z); s[3] = (short)f2bf(a.w);
            s[4] = (short)f2bf(b.x); s[5] = (short)f2bf(b.y);
            s[6] = (short)f2bf(b.z); s[7] = (short)f2bf(b.w);
            *(short8*)(clip16 + base + i * 8) = s;
        }
    }
}

// MFMA GEMV: part[ks][b][o] = sum_{k in ks-range} Xeff[b,k] * Wb[o][k]
// XPART=0: Xeff = X16 (bf16 [64][2048])
// XPART=1: Xeff[b,k] = sum_s Xp[s][b][k] (+ xbias[k])  (f32 partials, sum then
//          one bf16 round — identical numerics to the old combine->stage path)
// Grid 256 = 8 ks x 32 o-tiles(64). 4 waves/block. NO launch_bounds cap (R5),
// slice-sum unroll bounded to 4 (R4 spill lesson).
template<int XPART, int XBIAS>
__global__ __launch_bounds__(256)
void mfma_gemv(const u16* __restrict__ X16, const float* __restrict__ Xp,
               const float* __restrict__ xbias, const u16* __restrict__ Wb,
               float* __restrict__ part)
{
    __shared__ short Xs[64][72];   // row stride 144B -> conflict-benign
    __shared__ short Ws[64][72];
    const int t  = threadIdx.x;
    const int nt = blockIdx.x & 31;
    const int ks = blockIdx.x >> 5;
    const int o0 = nt * 64;
    const int kb = ks * 256;
    const int wv = t >> 6;
    const int ln = t & 63;
    const int xr = t & 63;            // X stage: row
    const int xg = t >> 6;            // X stage: 16-col group
    const int wn = t >> 2;            // W stage: o-row
    const int wk = (t & 3) * 16;      // W stage: 16-k group

    f32x4 acc[4];
#pragma unroll
    for (int i = 0; i < 4; ++i)
#pragma unroll
        for (int j = 0; j < 4; ++j) acc[i][j] = 0.f;

    uint4  qx[2];
    float4 px[4];
    uint4  pw[2];
    auto gload = [&](int k0) {
        if (!XPART) {
            qx[0] = *(const uint4*)(X16 + (size_t)xr * Hdim + k0 + xg * 16);
            qx[1] = *(const uint4*)(X16 + (size_t)xr * Hdim + k0 + xg * 16 + 8);
        } else {
#pragma unroll
            for (int i = 0; i < 4; ++i) {
                if (XBIAS) px[i] = *(const float4*)(xbias + k0 + xg * 16 + i * 4);
                else       px[i] = make_float4(0.f, 0.f, 0.f, 0.f);
            }
#pragma unroll 4
            for (int s = 0; s < KSPLIT; ++s) {
#pragma unroll
                for (int i = 0; i < 4; ++i) {
                    float4 p = *(const float4*)(Xp + (size_t)(s * 64 + xr) * Hdim + k0 + xg * 16 + i * 4);
                    px[i].x += p.x; px[i].y += p.y; px[i].z += p.z; px[i].w += p.w;
                }
            }
        }
        pw[0] = *(const uint4*)(Wb + (size_t)(o0 + wn) * Hdim + k0 + wk);
        pw[1] = *(const uint4*)(Wb + (size_t)(o0 + wn) * Hdim + k0 + wk + 8);
    };
    auto lstore = [&]() {
        if (!XPART) {
            *(uint4*)(&Xs[xr][xg * 16])     = qx[0];
            *(uint4*)(&Xs[xr][xg * 16 + 8]) = qx[1];
        } else {
#pragma unroll
            for (int i = 0; i < 2; ++i) {
                short8 s;
                s[0] = (short)f2bf(px[i*2].x);   s[1] = (short)f2bf(px[i*2].y);
                s[2] = (short)f2bf(px[i*2].z);   s[3] = (short)f2bf(px[i*2].w);
                s[4] = (short)f2bf(px[i*2+1].x); s[5] = (short)f2bf(px[i*2+1].y);
                s[6] = (short)f2bf(px[i*2+1].z); s[7] = (short)f2bf(px[i*2+1].w);
                *(short8*)(&Xs[xr][xg * 16 + i * 8]) = s;
            }
        }
        *(uint4*)(&Ws[wn][wk])     = pw[0];
        *(uint4*)(&Ws[wn][wk + 8]) = pw[1];
    };

    gload(kb);
    for (int c = 0; c < 4; ++c) {
        __syncthreads();
        lstore();
        __syncthreads();
        if (c < 3) gload(kb + (c + 1) * 64);
#pragma unroll
        for (int kstep = 0; kstep < 2; ++kstep) {
            const int kf = kstep * 32 + (ln >> 4) * 8;
            short8 af = *(const short8*)(&Xs[16 * wv + (ln & 15)][kf]);
#pragma unroll
            for (int n4 = 0; n4 < 4; ++n4) {
                short8 bf = *(const short8*)(&Ws[n4 * 16 + (ln & 15)][kf]);
                acc[n4] = __builtin_amdgcn_mfma_f32_16x16x32_bf16(af, bf, acc[n4], 0, 0, 0);
            }
        }
    }
#pragma unroll
    for (int n4 = 0; n4 < 4; ++n4) {
#pragma unroll
        for (int r = 0; r < 4; ++r) {
            const int brow = 16 * wv + (ln >> 4) * 4 + r;
            part[(size_t)(ks * 64 + brow) * Hdim + o0 + n4 * 16 + (ln & 15)] = acc[n4][r];
        }
    }
}

// Y[b,o] (=|+=) sum_s part[s][b][o] + bias[o]; writes f32 Y, bf16 mirror Y16,
// optionally out.
template<int ACC, int FINAL>
__global__ __launch_bounds__(256)
void combine(const float* __restrict__ part, const float* __restrict__ bias,
             float* __restrict__ Y, u16* __restrict__ Y16,
             float* __restrict__ out, int has_loss)
{
    const int flat4 = blockIdx.x * 256 + threadIdx.x;   // 0..32767
    const size_t e  = (size_t)flat4 * 4;
    const int o     = (int)(e & (Hdim - 1));
    float4 v = *(const float4*)(bias + o);
#pragma unroll
    for (int s = 0; s < KSPLIT; ++s) {
        float4 p = *(const float4*)(part + (size_t)s * (64 * Hdim) + e);
        v.x += p.x; v.y += p.y; v.z += p.z; v.w += p.w;
    }
    if (ACC) {
        float4 a = *(const float4*)(Y + e);
        v.x += a.x; v.y += a.y; v.z += a.z; v.w += a.w;
    }
    *(float4*)(Y + e) = v;
    ushort4 m;
    m.x = f2bf(v.x); m.y = f2bf(v.y); m.z = f2bf(v.z); m.w = f2bf(v.w);
    *(ushort4*)(Y16 + e) = m;
    if (FINAL) {
        *(float4*)(out + e) = v;
        if (has_loss && flat4 == 0) out[Bdim * Hdim] = 0.f;
    }
}

// One (b, 8-row n-chunk): theta_l from partials, scores -> local softmax ->
// partial weighted sum (bf16). FIRST: read f32 lfb + write bf16 cache.
template<int FIRST>
__global__ __launch_bounds__(256, 4)
void flash_chunk(const float* __restrict__ lfb, const u16* __restrict__ lfb16r,
                 u16* __restrict__ lfb16w, const float* __restrict__ thpart,
                 float scale, u16* __restrict__ up,
                 float* __restrict__ wm, float* __restrict__ wz)
{
    __shared__ u16 T[NCHUNK][Hdim];   // 32 KB
    __shared__ float th[Hdim];        // 8 KB
    __shared__ float sc[NCHUNK];
    __shared__ float wts[NCHUNK];
    const int t  = threadIdx.x;
    const int b  = blockIdx.x >> 6;
    const int ch = blockIdx.x & 63;
    const size_t nbase = (size_t)b * Ndim + ch * NCHUNK;
#pragma unroll
    for (int i = 0; i < 16; ++i) {
        int flat4 = i * 256 + t;
        int row   = flat4 >> 9;
        int c4    = flat4 & 511;
        if (FIRST) {
            float4 v = *(const float4*)(lfb + (nbase + row) * Hdim + c4 * 4);
            ushort4 u4;
            u4.x = f2bf(v.x); u4.y = f2bf(v.y); u4.z = f2bf(v.z); u4.w = f2bf(v.w);
            *(ushort4*)(&T[row][c4 * 4]) = u4;
            *(ushort4*)(lfb16w + (nbase + row) * Hdim + c4 * 4) = u4;
        } else {
            ushort4 u4 = *(const ushort4*)(lfb16r + (nbase + row) * Hdim + c4 * 4);
            *(ushort4*)(&T[row][c4 * 4]) = u4;
        }
    }
#pragma unroll
    for (int i = 0; i < 2; ++i) {
        int c = (i * 256 + t) * 4;
        float4 v = make_float4(0.f, 0.f, 0.f, 0.f);
#pragma unroll
        for (int s = 0; s < KSPLIT; ++s) {
            float4 p = *(const float4*)(thpart + (size_t)(s * 64 + b) * Hdim + c);
            v.x += p.x; v.y += p.y; v.z += p.z; v.w += p.w;
        }
        *(float4*)(&th[c]) = v;
    }
    __syncthreads();
    const int wv = t >> 6, ln = t & 63;
#pragma unroll
    for (int q = 0; q < 2; ++q) {
        int n = wv * 2 + q;
        float a = 0.f;
#pragma unroll
        for (int i = 0; i < 8; ++i) {
            int c = ln * 4 + i * 256;
            ushort4 x = *(const ushort4*)(&T[n][c]);
            float4 y  = *(const float4*)(&th[c]);
            a += bf2f(x.x) * y.x + bf2f(x.y) * y.y + bf2f(x.z) * y.z + bf2f(x.w) * y.w;
        }
#pragma unroll
        for (int off = 32; off; off >>= 1) a += __shfl_xor(a, off, 64);
        if (ln == 0) sc[n] = a * scale;
    }
    __syncthreads();
    float m = sc[0];
#pragma unroll
    for (int n = 1; n < NCHUNK; ++n) m = fmaxf(m, sc[n]);
    if (t < NCHUNK) wts[t] = expf(sc[t] - m);
    __syncthreads();
    if (t == 0) {
        float z = 0.f;
#pragma unroll
        for (int n = 0; n < NCHUNK; ++n) z += wts[n];
        wm[blockIdx.x] = m;
        wz[blockIdx.x] = z;
    }
#pragma unroll
    for (int i = 0; i < 8; ++i) {
        int c = t + i * 256;
        float a = 0.f;
#pragma unroll
        for (int n = 0; n < NCHUNK; ++n) a += wts[n] * bf2f(T[n][c]);
        up[(size_t)blockIdx.x * Hdim + c] = f2bf(a);
    }
}

// Merge 64 chunk-softmaxes per b; write u directly as bf16 (only gemv reads it).
__global__ __launch_bounds__(256)
void flash_comb(const u16* __restrict__ up, const float* __restrict__ wm,
                const float* __restrict__ wz, u16* __restrict__ u16out)
{
    __shared__ float mm[64], zz[64], ee[64];
    const int t  = threadIdx.x;
    const int b  = blockIdx.x >> 3;
    const int sl = blockIdx.x & 7;
    if (t < 64) { mm[t] = wm[b * 64 + t]; zz[t] = wz[b * 64 + t]; }
    __syncthreads();
    float mg = mm[0];
#pragma unroll
    for (int i = 1; i < 64; ++i) mg = fmaxf(mg, mm[i]);
    if (t < 64) ee[t] = expf(mm[t] - mg);
    __syncthreads();
    float Z = 0.f;
#pragma unroll
    for (int i = 0; i < 64; ++i) Z += zz[i] * ee[i];
    const float inv = 1.f / Z;
    const int col = sl * 256 + t;
    float a = 0.f;
#pragma unroll 8
    for (int ch = 0; ch < 64; ++ch)
        a += ee[ch] * bf2f(up[(size_t)(b * 64 + ch) * Hdim + col]);
    u16out[(size_t)b * Hdim + col] = f2bf(a * inv);
}

// r16 = bf16(relu(layernorm(sum_s part[s][b][:] + bias)))
__global__ __launch_bounds__(256)
void ln_relu_part(const float* __restrict__ part, const float* __restrict__ bias,
                  u16* __restrict__ r16)
{
    __shared__ float trow[Hdim];
    __shared__ float red[8];
    const int t = threadIdx.x, b = blockIdx.x;
    float sum = 0.f, sq = 0.f;
#pragma unroll
    for (int i = 0; i < 2; ++i) {
        int c = (i * 256 + t) * 4;
        float4 v = *(const float4*)(bias + c);
#pragma unroll
        for (int s = 0; s < KSPLIT; ++s) {
            float4 p = *(const float4*)(part + ((size_t)(s * 64 + b)) * Hdim + c);
            v.x += p.x; v.y += p.y; v.z += p.z; v.w += p.w;
        }
        *(float4*)(&trow[c]) = v;
        sum += v.x + v.y + v.z + v.w;
        sq  += v.x * v.x + v.y * v.y + v.z * v.z + v.w * v.w;
    }
#pragma unroll
    for (int off = 32; off; off >>= 1) {
        sum += __shfl_xor(sum, off, 64);
        sq  += __shfl_xor(sq,  off, 64);
    }
    if ((t & 63) == 0) { red[t >> 6] = sum; red[4 + (t >> 6)] = sq; }
    __syncthreads();
    sum = red[0] + red[1] + red[2] + red[3];
    sq  = red[4] + red[5] + red[6] + red[7];
    const float mu   = sum * (1.f / Hdim);
    const float var  = sq * (1.f / Hdim) - mu * mu;
    const float rstd = rsqrtf(var + LNEPS);
#pragma unroll
    for (int i = 0; i < 2; ++i) {
        int c = (i * 256 + t) * 4;
        float4 v = *(const float4*)(&trow[c]);
        ushort4 o;
        o.x = f2bf(fmaxf(0.f, (v.x - mu) * rstd));
        o.y = f2bf(fmaxf(0.f, (v.y - mu) * rstd));
        o.z = f2bf(fmaxf(0.f, (v.z - mu) * rstd));
        o.w = f2bf(fmaxf(0.f, (v.w - mu) * rstd));
        *(ushort4*)(r16 + (size_t)b * Hdim + c) = o;
    }
}

extern "C" void kernel_launch(void* const* d_in, const int* in_sizes, int n_in,
                              void* d_out, int out_size, void* d_ws, size_t ws_size,
                              hipStream_t stream) {
    (void)in_sizes; (void)n_in; (void)ws_size;
    const float* clip = (const float*)d_in[0];
    const float* lfb  = (const float*)d_in[1];
    const float* Wc   = (const float*)d_in[2];
    const float* bc   = (const float*)d_in[3];
    const float* Wl   = (const float*)d_in[4];
    const float* bl   = (const float*)d_in[5];
    const float* Wt   = (const float*)d_in[6];
    const float* bt   = (const float*)d_in[7];
    const float* Wp   = (const float*)d_in[8];
    // d_in[9] = bp: cancels in softmax (per-row constant) -> unused
    const float* Wg   = (const float*)d_in[10];
    const float* bg   = (const float*)d_in[11];
    const float* Wo   = (const float*)d_in[12];
    const float* bo   = (const float*)d_in[13];
    float* out = (float*)d_out;

    // Workspace layout (f32 slots); u16 buffers counted in f32 slots.
    float* wsf    = (float*)d_ws;
    float* A      = wsf;                      // 131072
    u16*   A16    = (u16*)(wsf + 131072);     // 65536 slots
    u16*   ubuf   = (u16*)(wsf + 196608);     // 65536
    u16*   r16    = (u16*)(wsf + 262144);     // 65536
    u16*   clip16 = (u16*)(wsf + 327680);     // 65536
    float* wm     = wsf + 393216;             // 4096
    float* wz     = wsf + 397312;             // 4096
    float* PA     = wsf + 401408;             // 8*64*2048 = 1048576 -> 1449984
    float* PB     = wsf + 1449984;            // 1048576 -> 2498560
    u16*   up     = (u16*)(wsf + 2498560);    // 4194304 slots -> 6692864
    u16*   lfb16  = (u16*)(wsf + 6692864);    // 33554432 slots -> 40247296
    u16*   Wbf    = (u16*)(wsf + 40247296);   // 7*2097152 slots (~220 MB total)

    u16* bWc  = Wbf + (size_t)0 * WMAT_ELEMS;
    u16* bWt  = Wbf + (size_t)1 * WMAT_ELEMS;
    u16* bWl  = Wbf + (size_t)2 * WMAT_ELEMS;
    u16* bWg  = Wbf + (size_t)3 * WMAT_ELEMS;
    u16* bWo  = Wbf + (size_t)4 * WMAT_ELEMS;
    u16* bWpT = Wbf + (size_t)5 * WMAT_ELEMS;
    u16* bWlT = Wbf + (size_t)6 * WMAT_ELEMS;

    const float scale = 0.022097086912079608f;   // 1/sqrt(2048)
    dim3 blk(256);
    const int has_loss = (out_size > Bdim * Hdim) ? 1 : 0;

    // one-time: bf16 weight views + clip16
    convert_w<<<7200, blk, 0, stream>>>(Wc, Wt, Wl, Wg, Wo, Wp, clip, Wbf, clip16);

    // A = clip @ Wc^T + bc
    mfma_gemv<0,0><<<256, blk, 0, stream>>>(clip16, nullptr, nullptr, bWc, PA);
    combine<0,0><<<128, blk, 0, stream>>>(PA, bc, A, A16, nullptr, 0);

    for (int l = 0; l < 3; ++l) {
        // theta partials = A @ Wt^T         (bt folded into next stage)
        mfma_gemv<0,0><<<256, blk, 0, stream>>>(A16, nullptr, nullptr, bWt, PA);
        // thetap partials = (sum PA + bt) @ Wp
        mfma_gemv<1,1><<<256, blk, 0, stream>>>(nullptr, PA, bt, bWpT, PB);
        // thetal partials = (sum PB) @ Wl
        mfma_gemv<1,0><<<256, blk, 0, stream>>>(nullptr, PB, nullptr, bWlT, PA);
        // fused scores/softmax/weighted-sum (sums PA for theta_l)
        if (l == 0)
            flash_chunk<1><<<4096, blk, 0, stream>>>(lfb, nullptr, lfb16, PA, scale, up, wm, wz);
        else
            flash_chunk<0><<<4096, blk, 0, stream>>>(nullptr, lfb16, nullptr, PA, scale, up, wm, wz);
        flash_comb<<<512, blk, 0, stream>>>(up, wm, wz, ubuf);
        // s partials = u @ Wl^T             (bl folded into next stage)
        mfma_gemv<0,0><<<256, blk, 0, stream>>>(ubuf, nullptr, nullptr, bWl, PB);
        // t partials = (sum PB + bl) @ Wg^T (bg folded into LN)
        mfma_gemv<1,1><<<256, blk, 0, stream>>>(nullptr, PB, bl, bWg, PA);
        // r = relu(LN(sum PA + bg))
        ln_relu_part<<<64, blk, 0, stream>>>(PA, bg, r16);
        // o partials = r @ Wo^T; A += sum + bo  (last layer writes out + loss)
        mfma_gemv<0,0><<<256, blk, 0, stream>>>(r16, nullptr, nullptr, bWo, PB);
        if (l < 2)
            combine<1,0><<<128, blk, 0, stream>>>(PB, bo, A, A16, nullptr, 0);
        else
            combine<1,1><<<128, blk, 0, stream>>>(PB, bo, A, A16, out, has_loss);
    }
}